// Round 17
// baseline (1342.851 us; speedup 1.0000x reference)
//
#include <hip/hip_runtime.h>

typedef unsigned short ushort;
typedef __bf16 bf16x8 __attribute__((ext_vector_type(8)));
typedef float f32x4 __attribute__((ext_vector_type(4)));
typedef float f4 __attribute__((ext_vector_type(4)));
typedef unsigned short us8 __attribute__((ext_vector_type(8)));
typedef unsigned short us4 __attribute__((ext_vector_type(4)));
typedef unsigned u32x4v __attribute__((ext_vector_type(4)));

#define NPIX 127008   // 8*126*126
#define HDIM 126
#define WDIM 126

__device__ __forceinline__ float bf2f(ushort u) {
  unsigned v = ((unsigned)u) << 16;
  return __builtin_bit_cast(float, v);
}
__device__ __forceinline__ ushort f2bf(float f) {
  unsigned x = __builtin_bit_cast(unsigned, f);
  x += 0x7fffu + ((x >> 16) & 1u);
  return (ushort)(x >> 16);
}

// ---------------- converts ----------------
__global__ void k_cvt_x(const float* __restrict__ x, ushort* __restrict__ xb, int n8) {
  const int stride = gridDim.x * blockDim.x;
  for (int i = blockIdx.x * blockDim.x + threadIdx.x; i < n8; i += stride) {
    const f4 a = *(const f4*)&x[(size_t)i * 8];
    const f4 b = *(const f4*)&x[(size_t)i * 8 + 4];
    us8 o;
#pragma unroll
    for (int j = 0; j < 4; ++j) { o[j] = f2bf(a[j]); o[4 + j] = f2bf(b[j]); }
    *(us8*)&xb[(size_t)i * 8] = o;
  }
}

__global__ void k_cvt_wT(const float* __restrict__ in, ushort* __restrict__ out, int N, int K) {
  const int t = blockIdx.x * 256 + threadIdx.x;
  const int n = t / K, k = t - n * K;
  out[t] = f2bf(in[(size_t)k * N + n]);
}

// ---------------- CPB bias MLP ----------------
__device__ __forceinline__ float frel(int i) {
  const float v = (float)(i - 7) * (8.0f / 7.0f);
  const float a = log1pf(fabsf(v)) * 0.4808983469629878f; // 1/ln(8)
  return v < 0.f ? -a : a;
}

__global__ __launch_bounds__(256) void k_cpb1(const float* __restrict__ w0,
    const float* __restrict__ b0, const float* __restrict__ w1, float* __restrict__ tmp) {
  const int p = blockIdx.x * 4 + (threadIdx.x >> 6);
  const int lane = threadIdx.x & 63;
  if (p >= 225) return;
  const float r0 = frel(p / 15), r1 = frel(p % 15);
  float hv[8];
#pragma unroll
  for (int jj = 0; jj < 8; ++jj) {
    const int j = lane * 8 + jj;
    hv[jj] = fmaxf(0.f, r0 * w0[j] + r1 * w0[512 + j] + b0[j]);
  }
  for (int h = 0; h < 8; ++h) {
    float part = 0.f;
#pragma unroll
    for (int jj = 0; jj < 8; ++jj) part += hv[jj] * w1[(lane * 8 + jj) * 8 + h];
    for (int o = 32; o; o >>= 1) part += __shfl_xor(part, o);
    if (lane == 0) tmp[p * 8 + h] = 16.f / (1.f + __expf(-part));
  }
}

// biasV[h][ki][g][q][r] = bias[h][key=ki*16+g*4+r][q]  (MFMA C-fragment layout)
__global__ void k_cpb2(const float* __restrict__ tmp, float* __restrict__ biasV) {
  const int t = blockIdx.x * 256 + threadIdx.x; // 32768
  const int h = t >> 12, rest = t & 4095;
  const int ki = rest >> 10, g = (rest >> 8) & 3, q = (rest >> 2) & 63, r = rest & 3;
  const int key = ki * 16 + g * 4 + r;
  const int d0 = (q >> 3) - (key >> 3) + 7, d1 = (q & 7) - (key & 7) + 7;
  biasV[t] = tmp[(d0 * 15 + d1) * 8 + h];
}

// ---------------- bf16 MFMA GEMM: C[M,N] = A[M,K=256] * Bt[N,K]^T ----------------
#define GLL(g, l) __builtin_amdgcn_global_load_lds( \
    (const __attribute__((address_space(1))) void*)(g), \
    (__attribute__((address_space(3))) void*)(l), 16, 0, 0)

template <int OUTF, int NX>
__global__ __launch_bounds__(256) void k_gemm(const ushort* __restrict__ A,
                                              const ushort* __restrict__ Bt,
                                              void* __restrict__ Cv, int M, int N) {
  constexpr int K = 256;
  __shared__ ushort lsA[128 * 64];
  __shared__ ushort lsB[128 * 64];
  const int tid = threadIdx.x;
  const int wid = tid >> 6, lane = tid & 63;

  const int nwg = gridDim.x;
  const int q8 = nwg >> 3, r8 = nwg & 7;
  const int xcd = blockIdx.x & 7, pos = blockIdx.x >> 3;
  const int lin = (xcd < r8) ? xcd * (q8 + 1) + pos
                             : r8 * (q8 + 1) + (xcd - r8) * q8 + pos;
  const int m0 = (lin / NX) * 128, n0 = (lin % NX) * 128;

  f32x4 acc[4][4];
#pragma unroll
  for (int i = 0; i < 4; ++i)
#pragma unroll
    for (int j = 0; j < 4; ++j) acc[i][j] = 0.f;

  const int srow = tid >> 3, sk = (tid & 7) * 8;
  const int aw = (wid >> 1) * 64, bw = (wid & 1) * 64;
  const int fr = lane & 15, kg = (lane >> 4) * 8;
  char* lA = (char*)lsA + wid * 1024;
  char* lB = (char*)lsB + wid * 1024;

  int ra[4];
#pragma unroll
  for (int c = 0; c < 4; ++c) {
    int r = m0 + c * 32 + srow;
    ra[c] = r < M ? r : M - 1;
  }
  const int rb0 = n0 + srow;

  for (int kt = 0; kt < K; kt += 64) {
    __syncthreads();
#pragma unroll
    for (int c = 0; c < 4; ++c) {
      GLL(A + (size_t)ra[c] * K + kt + sk, lA + c * 4096);
      GLL(Bt + (size_t)(rb0 + c * 32) * K + kt + sk, lB + c * 4096);
    }
    __syncthreads();
    bf16x8 af[2][4], bb[2][4];
#pragma unroll
    for (int kk = 0; kk < 2; ++kk)
#pragma unroll
      for (int i = 0; i < 4; ++i) {
        af[kk][i] = *(const bf16x8*)&lsA[(aw + i * 16 + fr) * 64 + kk * 32 + kg];
        bb[kk][i] = *(const bf16x8*)&lsB[(bw + i * 16 + fr) * 64 + kk * 32 + kg];
      }
#pragma unroll
    for (int kk = 0; kk < 2; ++kk)
#pragma unroll
      for (int i = 0; i < 4; ++i)
#pragma unroll
        for (int j = 0; j < 4; ++j)
          acc[i][j] = __builtin_amdgcn_mfma_f32_16x16x32_bf16(af[kk][i], bb[kk][j], acc[i][j], 0, 0, 0);
  }

  const int r4 = (lane >> 4) * 4, cc = lane & 15;
#pragma unroll
  for (int i = 0; i < 4; ++i) {
#pragma unroll
    for (int j = 0; j < 4; ++j) {
      const int gc = n0 + bw + j * 16 + cc;
#pragma unroll
      for (int r = 0; r < 4; ++r) {
        const int gr = m0 + aw + i * 16 + r4 + r;
        if (gr < M) {
          if constexpr (OUTF == 0)
            ((ushort*)Cv)[(size_t)gr * N + gc] = f2bf(acc[i][j][r]);
          else
            ((float*)Cv)[(size_t)gr * N + gc] = acc[i][j][r];
        }
      }
    }
  }
}

// ------- FUSED sliding conv3x3 + LN + bias + l2n + scale + window scatter -------
// v5: OCCUPANCY EXPERIMENT. Measured occupancy across all rounds fits
// waves/SIMD = floor(512/(2*VGPR)) -- convln at VGPR 76 is stuck at 3
// waves/SIMD. Force VGPR<=64 via __launch_bounds__(192,8); epilogue constants
// (gamma/beta/addb, 12 f32) move to a per-thread LDS slot (no barrier needed,
// thread-private) so the allocator has slack without scratch spills.
__global__ __launch_bounds__(192, 8) void k_convln(const ushort* __restrict__ pre,
    const float* __restrict__ wdw,
    const float* __restrict__ gamma, const float* __restrict__ beta,
    const float* __restrict__ qb, const float* __restrict__ vb,
    const float* __restrict__ scale, ushort* __restrict__ qkvw) {
  __shared__ __align__(16) float red[2][3][4];  // [parity][wave][{s0,q0,s1,q1}]
  __shared__ __align__(16) f4 epi[192][3];      // [chunk][{gamma,beta,addb}]
  const int nwg = gridDim.x;                    // 21168 = 8 * 2646
  const int q8 = nwg >> 3, r8 = nwg & 7;
  const int xcd = blockIdx.x & 7, pos = blockIdx.x >> 3;
  const int lin = (xcd < r8) ? xcd * (q8 + 1) + pos
                             : r8 * (q8 + 1) + (xcd - r8) * q8 + pos;
  const int rowid = lin % 1008;
  const int seg = lin / 1008;                   // 0..20
  const int b = rowid / HDIM, h = rowid - b * HDIM;
  const int chunk = threadIdx.x;                // 0..191
  const int wid = chunk >> 6, lane = chunk & 63;
  const int c0 = chunk * 4;

  // epilogue constants -> thread-private LDS slot (frees ~12 VGPRs)
  {
    f4 gg = *(const f4*)&gamma[c0];
    f4 bb = *(const f4*)&beta[c0];
    f4 ab = {0.f, 0.f, 0.f, 0.f};
    if (wid == 0) ab = *(const f4*)&qb[c0];
    if (wid == 2) ab = *(const f4*)&vb[c0 - 512];
    epi[chunk][0] = gg;
    epi[chunk][1] = bb;
    epi[chunk][2] = ab;
  }
  const float ls = (wid == 0) ? __expf(fminf(scale[chunk >> 3], 4.60517025f)) : 1.f;

  float wt[9][4];
#pragma unroll
  for (int tap = 0; tap < 9; ++tap) {
    const f4 wa = *(const f4*)&wdw[tap * 768 + c0];
#pragma unroll
    for (int j = 0; j < 4; ++j) wt[tap][j] = wa[j];
  }
  if (h == 0) {
#pragma unroll
    for (int tap = 0; tap < 3; ++tap)
#pragma unroll
      for (int j = 0; j < 4; ++j) wt[tap][j] = 0.f;
  }
  if (h == HDIM - 1) {
#pragma unroll
    for (int tap = 6; tap < 9; ++tap)
#pragma unroll
      for (int j = 0; j < 4; ++j) wt[tap][j] = 0.f;
  }

  const int hm = h > 0 ? h - 1 : 0, hp2 = h < HDIM - 1 ? h + 1 : HDIM - 1;
  const ushort* r0 = pre + (size_t)((b * HDIM + hm) * WDIM) * 768 + c0;
  const ushort* r1 = pre + (size_t)((b * HDIM + h) * WDIM) * 768 + c0;
  const ushort* r2 = pre + (size_t)((b * HDIM + hp2) * WDIM) * 768 + c0;

  const int w0 = seg * 6;                       // 21 segs x 6 px = 126
  float n0[3][4], n1[3][4], n2[3][4], n3[3][4], n4[3][4], n5[3][4];

#define LOADCOL(dst, w)                                                   \
  {                                                                       \
    us4 u0 = *(const us4*)&r0[(size_t)(w) * 768];                         \
    us4 u1 = *(const us4*)&r1[(size_t)(w) * 768];                         \
    us4 u2 = *(const us4*)&r2[(size_t)(w) * 768];                         \
    _Pragma("unroll") for (int j = 0; j < 4; ++j) {                       \
      dst[0][j] = bf2f(u0[j]); dst[1][j] = bf2f(u1[j]); dst[2][j] = bf2f(u2[j]); } \
  }
#define ZEROCOL(dst)                                                      \
  { _Pragma("unroll") for (int rr = 0; rr < 3; ++rr)                      \
    _Pragma("unroll") for (int j = 0; j < 4; ++j) dst[rr][j] = 0.f; }

  if (w0 > 0) { LOADCOL(n0, w0 - 1) } else { ZEROCOL(n0) }
  LOADCOL(n1, w0)
  LOADCOL(n2, w0 + 1)
  LOADCOL(n3, w0 + 2)

  const int dstc = ((b << 8) + (((h + 1) & 15) << 4)) << 6;
  const int dsth = ((h + 1) >> 4) << 3;

#define EPI(acc, tS, tQ, wp_)                                             \
  {                                                                       \
    const float mu = (tS) * (1.f / 768.f);                                \
    const float var = (tQ) * (1.f / 768.f) - mu * mu;                     \
    const float rs = rsqrtf(var + 1e-5f);                                 \
    const f4 gg = epi[chunk][0];                                          \
    const f4 bb4 = epi[chunk][1];                                         \
    const f4 ab = epi[chunk][2];                                          \
    float y[4];                                                           \
    _Pragma("unroll") for (int j = 0; j < 4; ++j)                         \
      y[j] = (acc[j] - mu) * rs * gg[j] + bb4[j] + ab[j];                 \
    if (wid < 2) {                                                        \
      float gq = y[0]*y[0] + y[1]*y[1] + y[2]*y[2] + y[3]*y[3];           \
      gq += __shfl_xor(gq, 1); gq += __shfl_xor(gq, 2); gq += __shfl_xor(gq, 4); \
      const float rn = rsqrtf(fmaxf(gq, 1.55e-5f)) * ls;                  \
      _Pragma("unroll") for (int j = 0; j < 4; ++j) y[j] *= rn;           \
    }                                                                     \
    const int dstrow = dstc + (((wp_) & 15) << 6) + dsth + ((wp_) >> 4);  \
    us4 o;                                                                \
    _Pragma("unroll") for (int j = 0; j < 4; ++j) o[j] = f2bf(y[j]);      \
    *(us4*)&qkvw[(size_t)dstrow * 768 + c0] = o;                          \
  }

#define CORE(A, B, C, D, w)                                               \
    float a0[4], a1[4];                                                   \
    _Pragma("unroll") for (int j = 0; j < 4; ++j) {                       \
      a0[j] = A[0][j]*wt[0][j] + B[0][j]*wt[1][j] + C[0][j]*wt[2][j]      \
            + A[1][j]*wt[3][j] + B[1][j]*wt[4][j] + C[1][j]*wt[5][j]      \
            + A[2][j]*wt[6][j] + B[2][j]*wt[7][j] + C[2][j]*wt[8][j];     \
      a1[j] = B[0][j]*wt[0][j] + C[0][j]*wt[1][j] + D[0][j]*wt[2][j]      \
            + B[1][j]*wt[3][j] + C[1][j]*wt[4][j] + D[1][j]*wt[5][j]      \
            + B[2][j]*wt[6][j] + C[2][j]*wt[7][j] + D[2][j]*wt[8][j];     \
    }                                                                     \
    float s0 = a0[0]+a0[1]+a0[2]+a0[3];                                   \
    float p0 = a0[0]*a0[0]+a0[1]*a0[1]+a0[2]*a0[2]+a0[3]*a0[3];           \
    float s1 = a1[0]+a1[1]+a1[2]+a1[3];                                   \
    float p1 = a1[0]*a1[0]+a1[1]*a1[1]+a1[2]*a1[2]+a1[3]*a1[3];           \
    _Pragma("unroll") for (int o = 32; o; o >>= 1) {                      \
      s0 += __shfl_xor(s0, o); p0 += __shfl_xor(p0, o);                   \
      s1 += __shfl_xor(s1, o); p1 += __shfl_xor(p1, o); }                 \
    const int par = ((w) >> 1) & 1;                                       \
    if (lane == 0) { f4 rv = {s0, p0, s1, p1}; *(f4*)&red[par][wid][0] = rv; } \
    asm volatile("s_waitcnt lgkmcnt(0)" ::: "memory");                    \
    __builtin_amdgcn_s_barrier();                                         \
    asm volatile("" ::: "memory");                                        \
    const float t0 = red[par][0][0] + red[par][1][0] + red[par][2][0];    \
    const float u0_ = red[par][0][1] + red[par][1][1] + red[par][2][1];   \
    const float t1 = red[par][0][2] + red[par][1][2] + red[par][2][2];    \
    const float u1_ = red[par][0][3] + red[par][1][3] + red[par][2][3];   \
    EPI(a0, t0, u0_, (w) + 1)                                             \
    EPI(a1, t1, u1_, (w) + 2)

#define PHASE(A, B, C, D, E, F, w)                                        \
  {                                                                       \
    if ((w) + 3 < WDIM) { LOADCOL(E, (w) + 3) } else { ZEROCOL(E) }       \
    if ((w) + 4 < WDIM) { LOADCOL(F, (w) + 4) } else { ZEROCOL(F) }       \
    CORE(A, B, C, D, w)                                                   \
  }
#define PHASE_LAST(A, B, C, D, w)                                         \
  {                                                                       \
    CORE(A, B, C, D, w)                                                   \
  }

  PHASE(n0, n1, n2, n3, n4, n5, w0)
  PHASE(n2, n3, n4, n5, n0, n1, w0 + 2)
  PHASE_LAST(n4, n5, n0, n1, w0 + 4)
#undef PHASE
#undef PHASE_LAST
#undef CORE
#undef EPI
#undef LOADCOL
#undef ZEROCOL
}

// ---------------- MFMA attention v4: window-major mapping ----------------
__global__ __launch_bounds__(256) void k_attn(const ushort* __restrict__ qkvw,
    const float* __restrict__ biasV, ushort* __restrict__ aout) {
  __shared__ ushort Vs[4][64][36];   // V natural layout, rows padded to 72B
  const int wid = threadIdx.x >> 6, lane = threadIdx.x & 63;
  const int linb = (blockIdx.x & 7) * 512 + (blockIdx.x >> 3);  // 4096 = 8*512
  const int u = linb * 4 + wid;
  const int head = u & 7, wl = u >> 3;
  const int b = wl >> 8, wh = (wl >> 4) & 15, ww = wl & 15;
  const int c = lane & 15, g = lane >> 4;
  const int g4 = g * 4, g8 = g * 8;
  const ushort* wb = qkvw + (size_t)wl * 64 * 768;
  const us8 zz = 0;

  const bool e_r0 = (wh == 0), e_r7 = (wh == 15), e_c0 = (ww == 0), e_c7 = (ww == 15);
#define TOKVALID(t) (!(((e_r0) & (((t) >> 3) == 0)) | ((e_r7) & (((t) >> 3) == 7)) | \
                       ((e_c0) & (((t) & 7) == 0)) | ((e_c7) & (((t) & 7) == 7))))

  // stage V (all 32 dims, masked)
  {
    const bool tv = TOKVALID(lane);
    const ushort* vp = wb + (size_t)lane * 768 + 512 + head * 32;
    us8 v0 = *(const us8*)vp;
    us8 v1 = *(const us8*)(vp + 8);
    us8 v2 = *(const us8*)(vp + 16);
    us8 v3 = *(const us8*)(vp + 24);
    v0 = tv ? v0 : zz;
    v1 = tv ? v1 : zz;
    v2 = tv ? v2 : zz;
    v3 = tv ? v3 : zz;
    ushort* vr = &Vs[wid][lane][0];
    *(us4*)&vr[0]  = __builtin_shufflevector(v0, v0, 0, 1, 2, 3);
    *(us4*)&vr[4]  = __builtin_shufflevector(v0, v0, 4, 5, 6, 7);
    *(us4*)&vr[8]  = __builtin_shufflevector(v1, v1, 0, 1, 2, 3);
    *(us4*)&vr[12] = __builtin_shufflevector(v1, v1, 4, 5, 6, 7);
    *(us4*)&vr[16] = __builtin_shufflevector(v2, v2, 0, 1, 2, 3);
    *(us4*)&vr[20] = __builtin_shufflevector(v2, v2, 4, 5, 6, 7);
    *(us4*)&vr[24] = __builtin_shufflevector(v3, v3, 0, 1, 2, 3);
    *(us4*)&vr[28] = __builtin_shufflevector(v3, v3, 4, 5, 6, 7);
  }

  // QK^T (swapped): A = K fragments, B = Q fragments; zero invalid fragments
  bf16x8 kf[4], qf[4];
#pragma unroll
  for (int ki = 0; ki < 4; ++ki) {
    const int tk = ki * 16 + c;
    us8 kv = *(const us8*)&wb[(size_t)tk * 768 + 256 + head * 32 + g8];
    kv = TOKVALID(tk) ? kv : zz;
    kf[ki] = __builtin_bit_cast(bf16x8, kv);
  }
#pragma unroll
  for (int qj = 0; qj < 4; ++qj) {
    const int tq = qj * 16 + c;
    us8 qv = *(const us8*)&wb[(size_t)tq * 768 + head * 32 + g8];
    qv = TOKVALID(tq) ? qv : zz;
    qf[qj] = __builtin_bit_cast(bf16x8, qv);
  }

  // bias fragment = MFMA C-input: biasV[head][ki][g][q][r]
  const float* bvh = biasV + (head << 12);
  f32x4 st[4][4];
#pragma unroll
  for (int ki = 0; ki < 4; ++ki)
#pragma unroll
    for (int qj = 0; qj < 4; ++qj) {
      const f32x4 bfrag = *(const f32x4*)&bvh[((ki * 4 + g) << 8) + ((qj * 16 + c) << 2)];
      st[ki][qj] = __builtin_amdgcn_mfma_f32_16x16x32_bf16(kf[ki], qf[qj], bfrag, 0, 0, 0);
    }

  // softmax + in-register P transpose
  unsigned afr[4][2][4];
#pragma unroll
  for (int qj = 0; qj < 4; ++qj) {
    float s[16];
#pragma unroll
    for (int ki = 0; ki < 4; ++ki)
#pragma unroll
      for (int r = 0; r < 4; ++r) {
        const int key = ki * 16 + g4 + r;
        s[ki * 4 + r] = TOKVALID(key) ? st[ki][qj][r] : -1e30f;
      }
    float m = s[0];
#pragma unroll
    for (int i = 1; i < 16; ++i) m = fmaxf(m, s[i]);
    m = fmaxf(m, __shfl_xor(m, 16));
    m = fmaxf(m, __shfl_xor(m, 32));
    float den = 0.f;
#pragma unroll
    for (int i = 0; i < 16; ++i) { s[i] = __expf(s[i] - m); den += s[i]; }
    den += __shfl_xor(den, 16);
    den += __shfl_xor(den, 32);
    const float inv = 1.f / den;

    unsigned pk[4][2];
#pragma unroll
    for (int ki = 0; ki < 4; ++ki) {
      pk[ki][0] = ((unsigned)f2bf(s[ki * 4 + 1] * inv) << 16) | f2bf(s[ki * 4 + 0] * inv);
      pk[ki][1] = ((unsigned)f2bf(s[ki * 4 + 3] * inv) << 16) | f2bf(s[ki * 4 + 2] * inv);
    }
#pragma unroll
    for (int j2 = 0; j2 < 4; ++j2) {
      const int src = c + 16 * (2 * (g & 1) + (j2 >> 1));
      const unsigned s0 = __shfl(pk[0][j2 & 1], src);
      const unsigned s1 = __shfl(pk[1][j2 & 1], src);
      const unsigned s2 = __shfl(pk[2][j2 & 1], src);
      const unsigned s3 = __shfl(pk[3][j2 & 1], src);
      afr[qj][0][j2] = (g < 2) ? s0 : s1;
      afr[qj][1][j2] = (g < 2) ? s2 : s3;
    }
  }

  // PV
  f32x4 ao[4][2];
#pragma unroll
  for (int qi = 0; qi < 4; ++qi)
#pragma unroll
    for (int di = 0; di < 2; ++di) ao[qi][di] = 0.f;
#pragma unroll
  for (int kc = 0; kc < 2; ++kc) {
#pragma unroll
    for (int di = 0; di < 2; ++di) {
      us8 bv;
#pragma unroll
      for (int j = 0; j < 8; ++j) bv[j] = Vs[wid][kc * 32 + g8 + j][di * 16 + c];
      const bf16x8 bb = __builtin_bit_cast(bf16x8, bv);
#pragma unroll
      for (int qi = 0; qi < 4; ++qi) {
        const u32x4v aw4 = {afr[qi][kc][0], afr[qi][kc][1], afr[qi][kc][2], afr[qi][kc][3]};
        ao[qi][di] = __builtin_amdgcn_mfma_f32_16x16x32_bf16(
            __builtin_bit_cast(bf16x8, aw4), bb, ao[qi][di], 0, 0, 0);
      }
    }
  }

#pragma unroll
  for (int qi = 0; qi < 4; ++qi)
#pragma unroll
    for (int r = 0; r < 4; ++r) {
      const int q = qi * 16 + g4 + r;
      if (TOKVALID(q)) {
        const int h = (q >> 3) * 16 + wh - 1, w2 = (q & 7) * 16 + ww - 1;
        ushort* op = aout + ((size_t)((b * HDIM + h) * WDIM + w2)) * 256 + head * 32;
        op[c] = f2bf(ao[qi][0][r]);
        op[16 + c] = f2bf(ao[qi][1][r]);
      }
    }
#undef TOKVALID
}

// ---------------- launch ----------------
extern "C" void kernel_launch(void* const* d_in, const int* in_sizes, int n_in,
                              void* d_out, int out_size, void* d_ws, size_t ws_size,
                              hipStream_t stream) {
  (void)in_sizes; (void)n_in; (void)out_size; (void)ws_size;
  const float* x      = (const float*)d_in[0];
  const float* w_qkv  = (const float*)d_in[1];
  const float* w_dw   = (const float*)d_in[2];
  const float* ln_g   = (const float*)d_in[3];
  const float* ln_b   = (const float*)d_in[4];
  const float* q_bias = (const float*)d_in[5];
  const float* v_bias = (const float*)d_in[6];
  const float* scale  = (const float*)d_in[7];
  const float* cpb_w0 = (const float*)d_in[8];
  const float* cpb_b0 = (const float*)d_in[9];
  const float* cpb_w1 = (const float*)d_in[10];
  const float* w_proj = (const float*)d_in[11];
  float* out = (float*)d_out;

  char* ws = (char*)d_ws;
  const size_t PRE  = (size_t)NPIX * 768 * 2;     // qkv_pre; reused for attn_out
  const size_t QKVW = (size_t)131072 * 768 * 2;   // window-padded qkv
  ushort* pre    = (ushort*)ws;
  ushort* qkvw   = (ushort*)(ws + PRE);
  ushort* xb     = (ushort*)(ws + PRE);           // bf16 x, parked in qkvw region
  ushort* aoutb  = pre;
  ushort* wqkvT  = (ushort*)(ws + PRE + QKVW);
  ushort* wprojT = (ushort*)(ws + PRE + QKVW + (size_t)768 * 256 * 2);
  float*  cpbtmp = (float*)(ws + PRE + QKVW + (size_t)768 * 256 * 2 + (size_t)256 * 256 * 2);
  float*  biasV  = (float*)(ws + PRE + QKVW + (size_t)768 * 256 * 2 + (size_t)256 * 256 * 2 + 8192);

  k_cvt_wT<<<768, 256, 0, stream>>>(w_qkv, wqkvT, 768, 256);
  k_cvt_wT<<<256, 256, 0, stream>>>(w_proj, wprojT, 256, 256);
  k_cpb1<<<57, 256, 0, stream>>>(cpb_w0, cpb_b0, cpb_w1, cpbtmp);
  k_cpb2<<<128, 256, 0, stream>>>(cpbtmp, biasV);
  k_cvt_x<<<2048, 256, 0, stream>>>(x, xb, NPIX * 256 / 8);
  k_gemm<0, 6><<<5958, 256, 0, stream>>>(xb, wqkvT, pre, NPIX, 768);
  k_convln<<<21168, 192, 0, stream>>>(pre, w_dw, ln_g, ln_b, q_bias, v_bias, scale, qkvw);
  k_attn<<<4096, 256, 0, stream>>>(qkvw, biasV, aoutb);
  k_gemm<1, 2><<<1986, 256, 0, stream>>>(aoutb, wprojT, out, NPIX, 256);
}

// Round 18
// 435.620 us; speedup vs baseline: 3.0826x; 3.0826x over previous
//
#include <hip/hip_runtime.h>

typedef unsigned short ushort;
typedef __bf16 bf16x8 __attribute__((ext_vector_type(8)));
typedef float f32x4 __attribute__((ext_vector_type(4)));
typedef float f4 __attribute__((ext_vector_type(4)));
typedef unsigned short us8 __attribute__((ext_vector_type(8)));
typedef unsigned short us4 __attribute__((ext_vector_type(4)));
typedef unsigned u32x4v __attribute__((ext_vector_type(4)));

#define NPIX 127008   // 8*126*126
#define HDIM 126
#define WDIM 126

__device__ __forceinline__ float bf2f(ushort u) {
  unsigned v = ((unsigned)u) << 16;
  return __builtin_bit_cast(float, v);
}
__device__ __forceinline__ ushort f2bf(float f) {
  unsigned x = __builtin_bit_cast(unsigned, f);
  x += 0x7fffu + ((x >> 16) & 1u);
  return (ushort)(x >> 16);
}

// ---------------- converts ----------------
__global__ void k_cvt_x(const float* __restrict__ x, ushort* __restrict__ xb, int n8) {
  const int stride = gridDim.x * blockDim.x;
  for (int i = blockIdx.x * blockDim.x + threadIdx.x; i < n8; i += stride) {
    const f4 a = *(const f4*)&x[(size_t)i * 8];
    const f4 b = *(const f4*)&x[(size_t)i * 8 + 4];
    us8 o;
#pragma unroll
    for (int j = 0; j < 4; ++j) { o[j] = f2bf(a[j]); o[4 + j] = f2bf(b[j]); }
    *(us8*)&xb[(size_t)i * 8] = o;
  }
}

__global__ void k_cvt_wT(const float* __restrict__ in, ushort* __restrict__ out, int N, int K) {
  const int t = blockIdx.x * 256 + threadIdx.x;
  const int n = t / K, k = t - n * K;
  out[t] = f2bf(in[(size_t)k * N + n]);
}

// ---------------- CPB bias MLP ----------------
__device__ __forceinline__ float frel(int i) {
  const float v = (float)(i - 7) * (8.0f / 7.0f);
  const float a = log1pf(fabsf(v)) * 0.4808983469629878f; // 1/ln(8)
  return v < 0.f ? -a : a;
}

__global__ __launch_bounds__(256) void k_cpb1(const float* __restrict__ w0,
    const float* __restrict__ b0, const float* __restrict__ w1, float* __restrict__ tmp) {
  const int p = blockIdx.x * 4 + (threadIdx.x >> 6);
  const int lane = threadIdx.x & 63;
  if (p >= 225) return;
  const float r0 = frel(p / 15), r1 = frel(p % 15);
  float hv[8];
#pragma unroll
  for (int jj = 0; jj < 8; ++jj) {
    const int j = lane * 8 + jj;
    hv[jj] = fmaxf(0.f, r0 * w0[j] + r1 * w0[512 + j] + b0[j]);
  }
  for (int h = 0; h < 8; ++h) {
    float part = 0.f;
#pragma unroll
    for (int jj = 0; jj < 8; ++jj) part += hv[jj] * w1[(lane * 8 + jj) * 8 + h];
    for (int o = 32; o; o >>= 1) part += __shfl_xor(part, o);
    if (lane == 0) tmp[p * 8 + h] = 16.f / (1.f + __expf(-part));
  }
}

// biasV[h][ki][g][q][r] = bias[h][key=ki*16+g*4+r][q]  (MFMA C-fragment layout)
__global__ void k_cpb2(const float* __restrict__ tmp, float* __restrict__ biasV) {
  const int t = blockIdx.x * 256 + threadIdx.x; // 32768
  const int h = t >> 12, rest = t & 4095;
  const int ki = rest >> 10, g = (rest >> 8) & 3, q = (rest >> 2) & 63, r = rest & 3;
  const int key = ki * 16 + g * 4 + r;
  const int d0 = (q >> 3) - (key >> 3) + 7, d1 = (q & 7) - (key & 7) + 7;
  biasV[t] = tmp[(d0 * 15 + d1) * 8 + h];
}

// ---------------- bf16 MFMA GEMM: C[M,N] = A[M,K=256] * Bt[N,K]^T ----------------
#define GLL(g, l) __builtin_amdgcn_global_load_lds( \
    (const __attribute__((address_space(1))) void*)(g), \
    (__attribute__((address_space(3))) void*)(l), 16, 0, 0)

template <int OUTF, int NX>
__global__ __launch_bounds__(256) void k_gemm(const ushort* __restrict__ A,
                                              const ushort* __restrict__ Bt,
                                              void* __restrict__ Cv, int M, int N) {
  constexpr int K = 256;
  __shared__ ushort lsA[128 * 64];
  __shared__ ushort lsB[128 * 64];
  const int tid = threadIdx.x;
  const int wid = tid >> 6, lane = tid & 63;

  const int nwg = gridDim.x;
  const int q8 = nwg >> 3, r8 = nwg & 7;
  const int xcd = blockIdx.x & 7, pos = blockIdx.x >> 3;
  const int lin = (xcd < r8) ? xcd * (q8 + 1) + pos
                             : r8 * (q8 + 1) + (xcd - r8) * q8 + pos;
  const int m0 = (lin / NX) * 128, n0 = (lin % NX) * 128;

  f32x4 acc[4][4];
#pragma unroll
  for (int i = 0; i < 4; ++i)
#pragma unroll
    for (int j = 0; j < 4; ++j) acc[i][j] = 0.f;

  const int srow = tid >> 3, sk = (tid & 7) * 8;
  const int aw = (wid >> 1) * 64, bw = (wid & 1) * 64;
  const int fr = lane & 15, kg = (lane >> 4) * 8;
  char* lA = (char*)lsA + wid * 1024;
  char* lB = (char*)lsB + wid * 1024;

  int ra[4];
#pragma unroll
  for (int c = 0; c < 4; ++c) {
    int r = m0 + c * 32 + srow;
    ra[c] = r < M ? r : M - 1;
  }
  const int rb0 = n0 + srow;

  for (int kt = 0; kt < K; kt += 64) {
    __syncthreads();
#pragma unroll
    for (int c = 0; c < 4; ++c) {
      GLL(A + (size_t)ra[c] * K + kt + sk, lA + c * 4096);
      GLL(Bt + (size_t)(rb0 + c * 32) * K + kt + sk, lB + c * 4096);
    }
    __syncthreads();
    bf16x8 af[2][4], bb[2][4];
#pragma unroll
    for (int kk = 0; kk < 2; ++kk)
#pragma unroll
      for (int i = 0; i < 4; ++i) {
        af[kk][i] = *(const bf16x8*)&lsA[(aw + i * 16 + fr) * 64 + kk * 32 + kg];
        bb[kk][i] = *(const bf16x8*)&lsB[(bw + i * 16 + fr) * 64 + kk * 32 + kg];
      }
#pragma unroll
    for (int kk = 0; kk < 2; ++kk)
#pragma unroll
      for (int i = 0; i < 4; ++i)
#pragma unroll
        for (int j = 0; j < 4; ++j)
          acc[i][j] = __builtin_amdgcn_mfma_f32_16x16x32_bf16(af[kk][i], bb[kk][j], acc[i][j], 0, 0, 0);
  }

  const int r4 = (lane >> 4) * 4, cc = lane & 15;
#pragma unroll
  for (int i = 0; i < 4; ++i) {
#pragma unroll
    for (int j = 0; j < 4; ++j) {
      const int gc = n0 + bw + j * 16 + cc;
#pragma unroll
      for (int r = 0; r < 4; ++r) {
        const int gr = m0 + aw + i * 16 + r4 + r;
        if (gr < M) {
          if constexpr (OUTF == 0)
            ((ushort*)Cv)[(size_t)gr * N + gc] = f2bf(acc[i][j][r]);
          else
            ((float*)Cv)[(size_t)gr * N + gc] = acc[i][j][r];
        }
      }
    }
  }
}

// ------- FUSED sliding conv3x3 + LN + bias + l2n + scale + window scatter -------
// v6: bf16 COLUMN BUFFERS. Round-17 experiment proved occupancy responds as
// waves ~ 512/(2*VGPR) (arch+acc pairing) and that at high occupancy this
// kernel gets ~4 TB/s -- but forcing VGPR via launch_bounds spilled to
// scratch. Here live state shrinks instead: columns stay bf16 (us4, 6 VGPR
// per buffer vs 12), converted at FMA time (lshl, free at 40% VALU). Same
// values, same arithmetic order -> bit-identical output.
__global__ __launch_bounds__(192) void k_convln(const ushort* __restrict__ pre,
    const float* __restrict__ wdw,
    const float* __restrict__ gamma, const float* __restrict__ beta,
    const float* __restrict__ qb, const float* __restrict__ vb,
    const float* __restrict__ scale, ushort* __restrict__ qkvw) {
  __shared__ __align__(16) float red[2][3][4];  // [parity][wave][{s0,q0,s1,q1}]
  const int nwg = gridDim.x;                    // 21168 = 8 * 2646
  const int q8 = nwg >> 3, r8 = nwg & 7;
  const int xcd = blockIdx.x & 7, pos = blockIdx.x >> 3;
  const int lin = (xcd < r8) ? xcd * (q8 + 1) + pos
                             : r8 * (q8 + 1) + (xcd - r8) * q8 + pos;
  const int rowid = lin % 1008;
  const int seg = lin / 1008;                   // 0..20
  const int b = rowid / HDIM, h = rowid - b * HDIM;
  const int chunk = threadIdx.x;                // 0..191
  const int wid = chunk >> 6, lane = chunk & 63;
  const int c0 = chunk * 4;

  float wt[9][4];
#pragma unroll
  for (int tap = 0; tap < 9; ++tap) {
    const f4 wa = *(const f4*)&wdw[tap * 768 + c0];
#pragma unroll
    for (int j = 0; j < 4; ++j) wt[tap][j] = wa[j];
  }
  if (h == 0) {
#pragma unroll
    for (int tap = 0; tap < 3; ++tap)
#pragma unroll
      for (int j = 0; j < 4; ++j) wt[tap][j] = 0.f;
  }
  if (h == HDIM - 1) {
#pragma unroll
    for (int tap = 6; tap < 9; ++tap)
#pragma unroll
      for (int j = 0; j < 4; ++j) wt[tap][j] = 0.f;
  }

  const f4 g4 = *(const f4*)&gamma[c0];
  const f4 b4 = *(const f4*)&beta[c0];
  f4 addb = {0.f, 0.f, 0.f, 0.f};
  if (wid == 0) addb = *(const f4*)&qb[c0];
  if (wid == 2) addb = *(const f4*)&vb[c0 - 512];
  const float ls = (wid == 0) ? __expf(fminf(scale[chunk >> 3], 4.60517025f)) : 1.f;

  const int hm = h > 0 ? h - 1 : 0, hp2 = h < HDIM - 1 ? h + 1 : HDIM - 1;
  const ushort* r0 = pre + (size_t)((b * HDIM + hm) * WDIM) * 768 + c0;
  const ushort* r1 = pre + (size_t)((b * HDIM + h) * WDIM) * 768 + c0;
  const ushort* r2 = pre + (size_t)((b * HDIM + hp2) * WDIM) * 768 + c0;

  const int w0 = seg * 6;                       // 21 segs x 6 px = 126
  // column buffers: bf16, [row] -> us4 (6 VGPRs per buffer)
  us4 n0[3], n1[3], n2[3], n3[3], n4[3], n5[3];

#define LOADCOL(dst, w)                                                   \
  {                                                                       \
    dst[0] = *(const us4*)&r0[(size_t)(w) * 768];                         \
    dst[1] = *(const us4*)&r1[(size_t)(w) * 768];                         \
    dst[2] = *(const us4*)&r2[(size_t)(w) * 768];                         \
  }
#define ZEROCOL(dst)                                                      \
  { dst[0] = 0; dst[1] = 0; dst[2] = 0; }

  if (w0 > 0) { LOADCOL(n0, w0 - 1) } else { ZEROCOL(n0) }
  LOADCOL(n1, w0)
  LOADCOL(n2, w0 + 1)
  LOADCOL(n3, w0 + 2)

  const int dstc = ((b << 8) + (((h + 1) & 15) << 4)) << 6;
  const int dsth = ((h + 1) >> 4) << 3;

#define CV(col, row, j) bf2f(col[row][j])

#define EPI(acc, tS, tQ, wp_)                                             \
  {                                                                       \
    const float mu = (tS) * (1.f / 768.f);                                \
    const float var = (tQ) * (1.f / 768.f) - mu * mu;                     \
    const float rs = rsqrtf(var + 1e-5f);                                 \
    float y[4];                                                           \
    _Pragma("unroll") for (int j = 0; j < 4; ++j)                         \
      y[j] = (acc[j] - mu) * rs * g4[j] + b4[j] + addb[j];                \
    if (wid < 2) {                                                        \
      float gg = y[0]*y[0] + y[1]*y[1] + y[2]*y[2] + y[3]*y[3];           \
      gg += __shfl_xor(gg, 1); gg += __shfl_xor(gg, 2); gg += __shfl_xor(gg, 4); \
      const float rn = rsqrtf(fmaxf(gg, 1.55e-5f)) * ls;                  \
      _Pragma("unroll") for (int j = 0; j < 4; ++j) y[j] *= rn;           \
    }                                                                     \
    const int dstrow = dstc + (((wp_) & 15) << 6) + dsth + ((wp_) >> 4);  \
    us4 o;                                                                \
    _Pragma("unroll") for (int j = 0; j < 4; ++j) o[j] = f2bf(y[j]);      \
    *(us4*)&qkvw[(size_t)dstrow * 768 + c0] = o;                          \
  }

#define CORE(A, B, C, D, w)                                               \
    float a0[4], a1[4];                                                   \
    _Pragma("unroll") for (int j = 0; j < 4; ++j) {                       \
      const float bv0 = CV(B,0,j), bv1 = CV(B,1,j), bv2 = CV(B,2,j);      \
      const float cv0 = CV(C,0,j), cv1 = CV(C,1,j), cv2 = CV(C,2,j);      \
      a0[j] = CV(A,0,j)*wt[0][j] + bv0*wt[1][j] + cv0*wt[2][j]            \
            + CV(A,1,j)*wt[3][j] + bv1*wt[4][j] + cv1*wt[5][j]            \
            + CV(A,2,j)*wt[6][j] + bv2*wt[7][j] + cv2*wt[8][j];           \
      a1[j] = bv0*wt[0][j] + cv0*wt[1][j] + CV(D,0,j)*wt[2][j]            \
            + bv1*wt[3][j] + cv1*wt[4][j] + CV(D,1,j)*wt[5][j]            \
            + bv2*wt[6][j] + cv2*wt[7][j] + CV(D,2,j)*wt[8][j];           \
    }                                                                     \
    float s0 = a0[0]+a0[1]+a0[2]+a0[3];                                   \
    float p0 = a0[0]*a0[0]+a0[1]*a0[1]+a0[2]*a0[2]+a0[3]*a0[3];           \
    float s1 = a1[0]+a1[1]+a1[2]+a1[3];                                   \
    float p1 = a1[0]*a1[0]+a1[1]*a1[1]+a1[2]*a1[2]+a1[3]*a1[3];           \
    _Pragma("unroll") for (int o = 32; o; o >>= 1) {                      \
      s0 += __shfl_xor(s0, o); p0 += __shfl_xor(p0, o);                   \
      s1 += __shfl_xor(s1, o); p1 += __shfl_xor(p1, o); }                 \
    const int par = ((w) >> 1) & 1;                                       \
    if (lane == 0) { f4 rv = {s0, p0, s1, p1}; *(f4*)&red[par][wid][0] = rv; } \
    asm volatile("s_waitcnt lgkmcnt(0)" ::: "memory");                    \
    __builtin_amdgcn_s_barrier();                                         \
    asm volatile("" ::: "memory");                                        \
    const float t0 = red[par][0][0] + red[par][1][0] + red[par][2][0];    \
    const float u0_ = red[par][0][1] + red[par][1][1] + red[par][2][1];   \
    const float t1 = red[par][0][2] + red[par][1][2] + red[par][2][2];    \
    const float u1_ = red[par][0][3] + red[par][1][3] + red[par][2][3];   \
    EPI(a0, t0, u0_, (w) + 1)                                             \
    EPI(a1, t1, u1_, (w) + 2)

#define PHASE(A, B, C, D, E, F, w)                                        \
  {                                                                       \
    if ((w) + 3 < WDIM) { LOADCOL(E, (w) + 3) } else { ZEROCOL(E) }       \
    if ((w) + 4 < WDIM) { LOADCOL(F, (w) + 4) } else { ZEROCOL(F) }       \
    CORE(A, B, C, D, w)                                                   \
  }
#define PHASE_LAST(A, B, C, D, w)                                         \
  {                                                                       \
    CORE(A, B, C, D, w)                                                   \
  }

  PHASE(n0, n1, n2, n3, n4, n5, w0)
  PHASE(n2, n3, n4, n5, n0, n1, w0 + 2)
  PHASE_LAST(n4, n5, n0, n1, w0 + 4)
#undef PHASE
#undef PHASE_LAST
#undef CORE
#undef EPI
#undef CV
#undef LOADCOL
#undef ZEROCOL
}

// ---------------- MFMA attention v4: window-major mapping ----------------
__global__ __launch_bounds__(256) void k_attn(const ushort* __restrict__ qkvw,
    const float* __restrict__ biasV, ushort* __restrict__ aout) {
  __shared__ ushort Vs[4][64][36];   // V natural layout, rows padded to 72B
  const int wid = threadIdx.x >> 6, lane = threadIdx.x & 63;
  const int linb = (blockIdx.x & 7) * 512 + (blockIdx.x >> 3);  // 4096 = 8*512
  const int u = linb * 4 + wid;
  const int head = u & 7, wl = u >> 3;
  const int b = wl >> 8, wh = (wl >> 4) & 15, ww = wl & 15;
  const int c = lane & 15, g = lane >> 4;
  const int g4 = g * 4, g8 = g * 8;
  const ushort* wb = qkvw + (size_t)wl * 64 * 768;
  const us8 zz = 0;

  const bool e_r0 = (wh == 0), e_r7 = (wh == 15), e_c0 = (ww == 0), e_c7 = (ww == 15);
#define TOKVALID(t) (!(((e_r0) & (((t) >> 3) == 0)) | ((e_r7) & (((t) >> 3) == 7)) | \
                       ((e_c0) & (((t) & 7) == 0)) | ((e_c7) & (((t) & 7) == 7))))

  // stage V (all 32 dims, masked)
  {
    const bool tv = TOKVALID(lane);
    const ushort* vp = wb + (size_t)lane * 768 + 512 + head * 32;
    us8 v0 = *(const us8*)vp;
    us8 v1 = *(const us8*)(vp + 8);
    us8 v2 = *(const us8*)(vp + 16);
    us8 v3 = *(const us8*)(vp + 24);
    v0 = tv ? v0 : zz;
    v1 = tv ? v1 : zz;
    v2 = tv ? v2 : zz;
    v3 = tv ? v3 : zz;
    ushort* vr = &Vs[wid][lane][0];
    *(us4*)&vr[0]  = __builtin_shufflevector(v0, v0, 0, 1, 2, 3);
    *(us4*)&vr[4]  = __builtin_shufflevector(v0, v0, 4, 5, 6, 7);
    *(us4*)&vr[8]  = __builtin_shufflevector(v1, v1, 0, 1, 2, 3);
    *(us4*)&vr[12] = __builtin_shufflevector(v1, v1, 4, 5, 6, 7);
    *(us4*)&vr[16] = __builtin_shufflevector(v2, v2, 0, 1, 2, 3);
    *(us4*)&vr[20] = __builtin_shufflevector(v2, v2, 4, 5, 6, 7);
    *(us4*)&vr[24] = __builtin_shufflevector(v3, v3, 0, 1, 2, 3);
    *(us4*)&vr[28] = __builtin_shufflevector(v3, v3, 4, 5, 6, 7);
  }

  // QK^T (swapped): A = K fragments, B = Q fragments; zero invalid fragments
  bf16x8 kf[4], qf[4];
#pragma unroll
  for (int ki = 0; ki < 4; ++ki) {
    const int tk = ki * 16 + c;
    us8 kv = *(const us8*)&wb[(size_t)tk * 768 + 256 + head * 32 + g8];
    kv = TOKVALID(tk) ? kv : zz;
    kf[ki] = __builtin_bit_cast(bf16x8, kv);
  }
#pragma unroll
  for (int qj = 0; qj < 4; ++qj) {
    const int tq = qj * 16 + c;
    us8 qv = *(const us8*)&wb[(size_t)tq * 768 + head * 32 + g8];
    qv = TOKVALID(tq) ? qv : zz;
    qf[qj] = __builtin_bit_cast(bf16x8, qv);
  }

  // bias fragment = MFMA C-input: biasV[head][ki][g][q][r]
  const float* bvh = biasV + (head << 12);
  f32x4 st[4][4];
#pragma unroll
  for (int ki = 0; ki < 4; ++ki)
#pragma unroll
    for (int qj = 0; qj < 4; ++qj) {
      const f32x4 bfrag = *(const f32x4*)&bvh[((ki * 4 + g) << 8) + ((qj * 16 + c) << 2)];
      st[ki][qj] = __builtin_amdgcn_mfma_f32_16x16x32_bf16(kf[ki], qf[qj], bfrag, 0, 0, 0);
    }

  // softmax + in-register P transpose
  unsigned afr[4][2][4];
#pragma unroll
  for (int qj = 0; qj < 4; ++qj) {
    float s[16];
#pragma unroll
    for (int ki = 0; ki < 4; ++ki)
#pragma unroll
      for (int r = 0; r < 4; ++r) {
        const int key = ki * 16 + g4 + r;
        s[ki * 4 + r] = TOKVALID(key) ? st[ki][qj][r] : -1e30f;
      }
    float m = s[0];
#pragma unroll
    for (int i = 1; i < 16; ++i) m = fmaxf(m, s[i]);
    m = fmaxf(m, __shfl_xor(m, 16));
    m = fmaxf(m, __shfl_xor(m, 32));
    float den = 0.f;
#pragma unroll
    for (int i = 0; i < 16; ++i) { s[i] = __expf(s[i] - m); den += s[i]; }
    den += __shfl_xor(den, 16);
    den += __shfl_xor(den, 32);
    const float inv = 1.f / den;

    unsigned pk[4][2];
#pragma unroll
    for (int ki = 0; ki < 4; ++ki) {
      pk[ki][0] = ((unsigned)f2bf(s[ki * 4 + 1] * inv) << 16) | f2bf(s[ki * 4 + 0] * inv);
      pk[ki][1] = ((unsigned)f2bf(s[ki * 4 + 3] * inv) << 16) | f2bf(s[ki * 4 + 2] * inv);
    }
#pragma unroll
    for (int j2 = 0; j2 < 4; ++j2) {
      const int src = c + 16 * (2 * (g & 1) + (j2 >> 1));
      const unsigned s0 = __shfl(pk[0][j2 & 1], src);
      const unsigned s1 = __shfl(pk[1][j2 & 1], src);
      const unsigned s2 = __shfl(pk[2][j2 & 1], src);
      const unsigned s3 = __shfl(pk[3][j2 & 1], src);
      afr[qj][0][j2] = (g < 2) ? s0 : s1;
      afr[qj][1][j2] = (g < 2) ? s2 : s3;
    }
  }

  // PV
  f32x4 ao[4][2];
#pragma unroll
  for (int qi = 0; qi < 4; ++qi)
#pragma unroll
    for (int di = 0; di < 2; ++di) ao[qi][di] = 0.f;
#pragma unroll
  for (int kc = 0; kc < 2; ++kc) {
#pragma unroll
    for (int di = 0; di < 2; ++di) {
      us8 bv;
#pragma unroll
      for (int j = 0; j < 8; ++j) bv[j] = Vs[wid][kc * 32 + g8 + j][di * 16 + c];
      const bf16x8 bb = __builtin_bit_cast(bf16x8, bv);
#pragma unroll
      for (int qi = 0; qi < 4; ++qi) {
        const u32x4v aw4 = {afr[qi][kc][0], afr[qi][kc][1], afr[qi][kc][2], afr[qi][kc][3]};
        ao[qi][di] = __builtin_amdgcn_mfma_f32_16x16x32_bf16(
            __builtin_bit_cast(bf16x8, aw4), bb, ao[qi][di], 0, 0, 0);
      }
    }
  }

#pragma unroll
  for (int qi = 0; qi < 4; ++qi)
#pragma unroll
    for (int r = 0; r < 4; ++r) {
      const int q = qi * 16 + g4 + r;
      if (TOKVALID(q)) {
        const int h = (q >> 3) * 16 + wh - 1, w2 = (q & 7) * 16 + ww - 1;
        ushort* op = aout + ((size_t)((b * HDIM + h) * WDIM + w2)) * 256 + head * 32;
        op[c] = f2bf(ao[qi][0][r]);
        op[16 + c] = f2bf(ao[qi][1][r]);
      }
    }
#undef TOKVALID
}

// ---------------- launch ----------------
extern "C" void kernel_launch(void* const* d_in, const int* in_sizes, int n_in,
                              void* d_out, int out_size, void* d_ws, size_t ws_size,
                              hipStream_t stream) {
  (void)in_sizes; (void)n_in; (void)out_size; (void)ws_size;
  const float* x      = (const float*)d_in[0];
  const float* w_qkv  = (const float*)d_in[1];
  const float* w_dw   = (const float*)d_in[2];
  const float* ln_g   = (const float*)d_in[3];
  const float* ln_b   = (const float*)d_in[4];
  const float* q_bias = (const float*)d_in[5];
  const float* v_bias = (const float*)d_in[6];
  const float* scale  = (const float*)d_in[7];
  const float* cpb_w0 = (const float*)d_in[8];
  const float* cpb_b0 = (const float*)d_in[9];
  const float* cpb_w1 = (const float*)d_in[10];
  const float* w_proj = (const float*)d_in[11];
  float* out = (float*)d_out;

  char* ws = (char*)d_ws;
  const size_t PRE  = (size_t)NPIX * 768 * 2;     // qkv_pre; reused for attn_out
  const size_t QKVW = (size_t)131072 * 768 * 2;   // window-padded qkv
  ushort* pre    = (ushort*)ws;
  ushort* qkvw   = (ushort*)(ws + PRE);
  ushort* xb     = (ushort*)(ws + PRE);           // bf16 x, parked in qkvw region
  ushort* aoutb  = pre;
  ushort* wqkvT  = (ushort*)(ws + PRE + QKVW);
  ushort* wprojT = (ushort*)(ws + PRE + QKVW + (size_t)768 * 256 * 2);
  float*  cpbtmp = (float*)(ws + PRE + QKVW + (size_t)768 * 256 * 2 + (size_t)256 * 256 * 2);
  float*  biasV  = (float*)(ws + PRE + QKVW + (size_t)768 * 256 * 2 + (size_t)256 * 256 * 2 + 8192);

  k_cvt_wT<<<768, 256, 0, stream>>>(w_qkv, wqkvT, 768, 256);
  k_cvt_wT<<<256, 256, 0, stream>>>(w_proj, wprojT, 256, 256);
  k_cpb1<<<57, 256, 0, stream>>>(cpb_w0, cpb_b0, cpb_w1, cpbtmp);
  k_cpb2<<<128, 256, 0, stream>>>(cpbtmp, biasV);
  k_cvt_x<<<2048, 256, 0, stream>>>(x, xb, NPIX * 256 / 8);
  k_gemm<0, 6><<<5958, 256, 0, stream>>>(xb, wqkvT, pre, NPIX, 768);
  k_convln<<<21168, 192, 0, stream>>>(pre, w_dw, ln_g, ln_b, q_bias, v_bias, scale, qkvw);
  k_attn<<<4096, 256, 0, stream>>>(qkvw, biasV, aoutb);
  k_gemm<1, 2><<<1986, 256, 0, stream>>>(aoutb, wprojT, out, NPIX, 256);
}

// Round 19
// 430.858 us; speedup vs baseline: 3.1167x; 1.0111x over previous
//
#include <hip/hip_runtime.h>

typedef unsigned short ushort;
typedef __bf16 bf16x8 __attribute__((ext_vector_type(8)));
typedef float f32x4 __attribute__((ext_vector_type(4)));
typedef float f4 __attribute__((ext_vector_type(4)));
typedef unsigned short us8 __attribute__((ext_vector_type(8)));
typedef unsigned short us4 __attribute__((ext_vector_type(4)));
typedef unsigned u32x4v __attribute__((ext_vector_type(4)));

#define NPIX 127008   // 8*126*126
#define HDIM 126
#define WDIM 126

__device__ __forceinline__ float bf2f(ushort u) {
  unsigned v = ((unsigned)u) << 16;
  return __builtin_bit_cast(float, v);
}
__device__ __forceinline__ ushort f2bf(float f) {
  unsigned x = __builtin_bit_cast(unsigned, f);
  x += 0x7fffu + ((x >> 16) & 1u);
  return (ushort)(x >> 16);
}

// ---------------- converts ----------------
__global__ void k_cvt_x(const float* __restrict__ x, ushort* __restrict__ xb, int n8) {
  const int stride = gridDim.x * blockDim.x;
  for (int i = blockIdx.x * blockDim.x + threadIdx.x; i < n8; i += stride) {
    const f4 a = *(const f4*)&x[(size_t)i * 8];
    const f4 b = *(const f4*)&x[(size_t)i * 8 + 4];
    us8 o;
#pragma unroll
    for (int j = 0; j < 4; ++j) { o[j] = f2bf(a[j]); o[4 + j] = f2bf(b[j]); }
    *(us8*)&xb[(size_t)i * 8] = o;
  }
}

__global__ void k_cvt_wT(const float* __restrict__ in, ushort* __restrict__ out, int N, int K) {
  const int t = blockIdx.x * 256 + threadIdx.x;
  const int n = t / K, k = t - n * K;
  out[t] = f2bf(in[(size_t)k * N + n]);
}

// beta2 = beta + concat(q_bias, 0, v_bias)  (frees 4 VGPR + 8 VALU/px in convln)
__global__ void k_fuseb(const float* __restrict__ beta, const float* __restrict__ qb,
                        const float* __restrict__ vb, float* __restrict__ beta2) {
  const int i = blockIdx.x * 256 + threadIdx.x;   // 768
  const float add = (i < 256) ? qb[i] : (i < 512 ? 0.f : vb[i - 512]);
  beta2[i] = beta[i] + add;
}

// ---------------- CPB bias MLP ----------------
__device__ __forceinline__ float frel(int i) {
  const float v = (float)(i - 7) * (8.0f / 7.0f);
  const float a = log1pf(fabsf(v)) * 0.4808983469629878f; // 1/ln(8)
  return v < 0.f ? -a : a;
}

__global__ __launch_bounds__(256) void k_cpb1(const float* __restrict__ w0,
    const float* __restrict__ b0, const float* __restrict__ w1, float* __restrict__ tmp) {
  const int p = blockIdx.x * 4 + (threadIdx.x >> 6);
  const int lane = threadIdx.x & 63;
  if (p >= 225) return;
  const float r0 = frel(p / 15), r1 = frel(p % 15);
  float hv[8];
#pragma unroll
  for (int jj = 0; jj < 8; ++jj) {
    const int j = lane * 8 + jj;
    hv[jj] = fmaxf(0.f, r0 * w0[j] + r1 * w0[512 + j] + b0[j]);
  }
  for (int h = 0; h < 8; ++h) {
    float part = 0.f;
#pragma unroll
    for (int jj = 0; jj < 8; ++jj) part += hv[jj] * w1[(lane * 8 + jj) * 8 + h];
    for (int o = 32; o; o >>= 1) part += __shfl_xor(part, o);
    if (lane == 0) tmp[p * 8 + h] = 16.f / (1.f + __expf(-part));
  }
}

// biasV[h][ki][g][q][r] = bias[h][key=ki*16+g*4+r][q]  (MFMA C-fragment layout)
__global__ void k_cpb2(const float* __restrict__ tmp, float* __restrict__ biasV) {
  const int t = blockIdx.x * 256 + threadIdx.x; // 32768
  const int h = t >> 12, rest = t & 4095;
  const int ki = rest >> 10, g = (rest >> 8) & 3, q = (rest >> 2) & 63, r = rest & 3;
  const int key = ki * 16 + g * 4 + r;
  const int d0 = (q >> 3) - (key >> 3) + 7, d1 = (q & 7) - (key & 7) + 7;
  biasV[t] = tmp[(d0 * 15 + d1) * 8 + h];
}

// ---------------- bf16 MFMA GEMM: C[M,N] = A[M,K=256] * Bt[N,K]^T ----------------
#define GLL(g, l) __builtin_amdgcn_global_load_lds( \
    (const __attribute__((address_space(1))) void*)(g), \
    (__attribute__((address_space(3))) void*)(l), 16, 0, 0)

template <int OUTF, int NX>
__global__ __launch_bounds__(256) void k_gemm(const ushort* __restrict__ A,
                                              const ushort* __restrict__ Bt,
                                              void* __restrict__ Cv, int M, int N) {
  constexpr int K = 256;
  __shared__ ushort lsA[128 * 64];
  __shared__ ushort lsB[128 * 64];
  const int tid = threadIdx.x;
  const int wid = tid >> 6, lane = tid & 63;

  const int nwg = gridDim.x;
  const int q8 = nwg >> 3, r8 = nwg & 7;
  const int xcd = blockIdx.x & 7, pos = blockIdx.x >> 3;
  const int lin = (xcd < r8) ? xcd * (q8 + 1) + pos
                             : r8 * (q8 + 1) + (xcd - r8) * q8 + pos;
  const int m0 = (lin / NX) * 128, n0 = (lin % NX) * 128;

  f32x4 acc[4][4];
#pragma unroll
  for (int i = 0; i < 4; ++i)
#pragma unroll
    for (int j = 0; j < 4; ++j) acc[i][j] = 0.f;

  const int srow = tid >> 3, sk = (tid & 7) * 8;
  const int aw = (wid >> 1) * 64, bw = (wid & 1) * 64;
  const int fr = lane & 15, kg = (lane >> 4) * 8;
  char* lA = (char*)lsA + wid * 1024;
  char* lB = (char*)lsB + wid * 1024;

  int ra[4];
#pragma unroll
  for (int c = 0; c < 4; ++c) {
    int r = m0 + c * 32 + srow;
    ra[c] = r < M ? r : M - 1;
  }
  const int rb0 = n0 + srow;

  for (int kt = 0; kt < K; kt += 64) {
    __syncthreads();
#pragma unroll
    for (int c = 0; c < 4; ++c) {
      GLL(A + (size_t)ra[c] * K + kt + sk, lA + c * 4096);
      GLL(Bt + (size_t)(rb0 + c * 32) * K + kt + sk, lB + c * 4096);
    }
    __syncthreads();
    bf16x8 af[2][4], bb[2][4];
#pragma unroll
    for (int kk = 0; kk < 2; ++kk)
#pragma unroll
      for (int i = 0; i < 4; ++i) {
        af[kk][i] = *(const bf16x8*)&lsA[(aw + i * 16 + fr) * 64 + kk * 32 + kg];
        bb[kk][i] = *(const bf16x8*)&lsB[(bw + i * 16 + fr) * 64 + kk * 32 + kg];
      }
#pragma unroll
    for (int kk = 0; kk < 2; ++kk)
#pragma unroll
      for (int i = 0; i < 4; ++i)
#pragma unroll
        for (int j = 0; j < 4; ++j)
          acc[i][j] = __builtin_amdgcn_mfma_f32_16x16x32_bf16(af[kk][i], bb[kk][j], acc[i][j], 0, 0, 0);
  }

  const int r4 = (lane >> 4) * 4, cc = lane & 15;
#pragma unroll
  for (int i = 0; i < 4; ++i) {
#pragma unroll
    for (int j = 0; j < 4; ++j) {
      const int gc = n0 + bw + j * 16 + cc;
#pragma unroll
      for (int r = 0; r < 4; ++r) {
        const int gr = m0 + aw + i * 16 + r4 + r;
        if (gr < M) {
          if constexpr (OUTF == 0)
            ((ushort*)Cv)[(size_t)gr * N + gc] = f2bf(acc[i][j][r]);
          else
            ((float*)Cv)[(size_t)gr * N + gc] = acc[i][j][r];
        }
      }
    }
  }
}

// ------- FUSED sliding conv3x3 + LN + bias + l2n + scale + window scatter -------
// v7: 4-buffer rotation (distance-1 prefetch: loads issue right after the FMA
// block that last reads the overwritten buffers; shuffle-reduce+barrier+EPI
// cover the latency) + beta2 fold. Target VGPR <= 51 -> 5 waves/SIMD.
__global__ __launch_bounds__(192) void k_convln(const ushort* __restrict__ pre,
    const float* __restrict__ wdw,
    const float* __restrict__ gamma, const float* __restrict__ beta2,
    const float* __restrict__ scale, ushort* __restrict__ qkvw) {
  __shared__ __align__(16) float red[2][3][4];  // [parity][wave][{s0,q0,s1,q1}]
  const int nwg = gridDim.x;                    // 21168 = 8 * 2646
  const int q8 = nwg >> 3, r8 = nwg & 7;
  const int xcd = blockIdx.x & 7, pos = blockIdx.x >> 3;
  const int lin = (xcd < r8) ? xcd * (q8 + 1) + pos
                             : r8 * (q8 + 1) + (xcd - r8) * q8 + pos;
  const int rowid = lin % 1008;
  const int seg = lin / 1008;                   // 0..20
  const int b = rowid / HDIM, h = rowid - b * HDIM;
  const int chunk = threadIdx.x;                // 0..191
  const int wid = chunk >> 6, lane = chunk & 63;
  const int c0 = chunk * 4;

  float wt[9][4];
#pragma unroll
  for (int tap = 0; tap < 9; ++tap) {
    const f4 wa = *(const f4*)&wdw[tap * 768 + c0];
#pragma unroll
    for (int j = 0; j < 4; ++j) wt[tap][j] = wa[j];
  }
  if (h == 0) {
#pragma unroll
    for (int tap = 0; tap < 3; ++tap)
#pragma unroll
      for (int j = 0; j < 4; ++j) wt[tap][j] = 0.f;
  }
  if (h == HDIM - 1) {
#pragma unroll
    for (int tap = 6; tap < 9; ++tap)
#pragma unroll
      for (int j = 0; j < 4; ++j) wt[tap][j] = 0.f;
  }

  const f4 g4 = *(const f4*)&gamma[c0];
  const f4 b2 = *(const f4*)&beta2[c0];
  const float ls = (wid == 0) ? __expf(fminf(scale[chunk >> 3], 4.60517025f)) : 1.f;

  const int hm = h > 0 ? h - 1 : 0, hp2 = h < HDIM - 1 ? h + 1 : HDIM - 1;
  const ushort* r0 = pre + (size_t)((b * HDIM + hm) * WDIM) * 768 + c0;
  const ushort* r1 = pre + (size_t)((b * HDIM + h) * WDIM) * 768 + c0;
  const ushort* r2 = pre + (size_t)((b * HDIM + hp2) * WDIM) * 768 + c0;

  const int w0 = seg * 6;                       // 21 segs x 6 px = 126
  // 4 column buffers, bf16 (us4 x 3 rows = 6 VGPR each)
  us4 n0[3], n1[3], n2[3], n3[3];

#define LOADCOL(dst, w)                                                   \
  {                                                                       \
    dst[0] = *(const us4*)&r0[(size_t)(w) * 768];                         \
    dst[1] = *(const us4*)&r1[(size_t)(w) * 768];                         \
    dst[2] = *(const us4*)&r2[(size_t)(w) * 768];                         \
  }
#define ZEROCOL(dst)                                                      \
  { dst[0] = 0; dst[1] = 0; dst[2] = 0; }
#define LOADG(dst, w)                                                     \
  { if ((w) < WDIM) { LOADCOL(dst, w) } else { ZEROCOL(dst) } }

  if (w0 > 0) { LOADCOL(n0, w0 - 1) } else { ZEROCOL(n0) }
  LOADCOL(n1, w0)
  LOADCOL(n2, w0 + 1)
  LOADCOL(n3, w0 + 2)

  const int dstc = ((b << 8) + (((h + 1) & 15) << 4)) << 6;
  const int dsth = ((h + 1) >> 4) << 3;

#define CV(col, row, j) bf2f(col[row][j])

#define EPI(acc, tS, tQ, wp_)                                             \
  {                                                                       \
    const float mu = (tS) * (1.f / 768.f);                                \
    const float var = (tQ) * (1.f / 768.f) - mu * mu;                     \
    const float rs = rsqrtf(var + 1e-5f);                                 \
    float y[4];                                                           \
    _Pragma("unroll") for (int j = 0; j < 4; ++j)                         \
      y[j] = (acc[j] - mu) * rs * g4[j] + b2[j];                          \
    if (wid < 2) {                                                        \
      float gg = y[0]*y[0] + y[1]*y[1] + y[2]*y[2] + y[3]*y[3];           \
      gg += __shfl_xor(gg, 1); gg += __shfl_xor(gg, 2); gg += __shfl_xor(gg, 4); \
      const float rn = rsqrtf(fmaxf(gg, 1.55e-5f)) * ls;                  \
      _Pragma("unroll") for (int j = 0; j < 4; ++j) y[j] *= rn;           \
    }                                                                     \
    const int dstrow = dstc + (((wp_) & 15) << 6) + dsth + ((wp_) >> 4);  \
    us4 o;                                                                \
    _Pragma("unroll") for (int j = 0; j < 4; ++j) o[j] = f2bf(y[j]);      \
    *(us4*)&qkvw[(size_t)dstrow * 768 + c0] = o;                          \
  }

// FMAS reads A..D; REST does reduce+barrier+EPIs. Prefetch loads go between.
#define FMAS(A, B, C, D)                                                  \
    float a0[4], a1[4];                                                   \
    _Pragma("unroll") for (int j = 0; j < 4; ++j) {                       \
      const float bv0 = CV(B,0,j), bv1 = CV(B,1,j), bv2 = CV(B,2,j);      \
      const float cv0 = CV(C,0,j), cv1 = CV(C,1,j), cv2 = CV(C,2,j);      \
      a0[j] = CV(A,0,j)*wt[0][j] + bv0*wt[1][j] + cv0*wt[2][j]            \
            + CV(A,1,j)*wt[3][j] + bv1*wt[4][j] + cv1*wt[5][j]            \
            + CV(A,2,j)*wt[6][j] + bv2*wt[7][j] + cv2*wt[8][j];           \
      a1[j] = bv0*wt[0][j] + cv0*wt[1][j] + CV(D,0,j)*wt[2][j]            \
            + bv1*wt[3][j] + cv1*wt[4][j] + CV(D,1,j)*wt[5][j]            \
            + bv2*wt[6][j] + cv2*wt[7][j] + CV(D,2,j)*wt[8][j];           \
    }

#define REST(w)                                                           \
    float s0 = a0[0]+a0[1]+a0[2]+a0[3];                                   \
    float p0 = a0[0]*a0[0]+a0[1]*a0[1]+a0[2]*a0[2]+a0[3]*a0[3];           \
    float s1 = a1[0]+a1[1]+a1[2]+a1[3];                                   \
    float p1 = a1[0]*a1[0]+a1[1]*a1[1]+a1[2]*a1[2]+a1[3]*a1[3];           \
    _Pragma("unroll") for (int o = 32; o; o >>= 1) {                      \
      s0 += __shfl_xor(s0, o); p0 += __shfl_xor(p0, o);                   \
      s1 += __shfl_xor(s1, o); p1 += __shfl_xor(p1, o); }                 \
    const int par = ((w) >> 1) & 1;                                       \
    if (lane == 0) { f4 rv = {s0, p0, s1, p1}; *(f4*)&red[par][wid][0] = rv; } \
    asm volatile("s_waitcnt lgkmcnt(0)" ::: "memory");                    \
    __builtin_amdgcn_s_barrier();                                         \
    asm volatile("" ::: "memory");                                        \
    const float t0 = red[par][0][0] + red[par][1][0] + red[par][2][0];    \
    const float u0_ = red[par][0][1] + red[par][1][1] + red[par][2][1];   \
    const float t1 = red[par][0][2] + red[par][1][2] + red[par][2][2];    \
    const float u1_ = red[par][0][3] + red[par][1][3] + red[par][2][3];   \
    EPI(a0, t0, u0_, (w) + 1)                                             \
    EPI(a1, t1, u1_, (w) + 2)

#define PHASE(A, B, C, D, P0, P1, w, lw)                                  \
  {                                                                       \
    FMAS(A, B, C, D)                                                      \
    LOADG(P0, lw)                                                         \
    LOADG(P1, (lw) + 1)                                                   \
    REST(w)                                                               \
  }
#define PHASE_LAST(A, B, C, D, w)                                         \
  {                                                                       \
    FMAS(A, B, C, D)                                                      \
    REST(w)                                                               \
  }

  // phase 1: px w0,w0+1 (cols w0-1..w0+2); prefetch w0+3,w0+4 into n0,n1
  PHASE(n0, n1, n2, n3, n0, n1, w0, w0 + 3)
  // phase 2: px w0+2,w0+3 (cols w0+1..w0+4 = n2,n3,n0,n1); prefetch w0+5,w0+6
  PHASE(n2, n3, n0, n1, n2, n3, w0 + 2, w0 + 5)
  // phase 3: px w0+4,w0+5 (cols w0+3..w0+6 = n0,n1,n2,n3)
  PHASE_LAST(n0, n1, n2, n3, w0 + 4)
#undef PHASE
#undef PHASE_LAST
#undef FMAS
#undef REST
#undef EPI
#undef CV
#undef LOADG
#undef LOADCOL
#undef ZEROCOL
}

// ---------------- MFMA attention v4: window-major mapping ----------------
__global__ __launch_bounds__(256) void k_attn(const ushort* __restrict__ qkvw,
    const float* __restrict__ biasV, ushort* __restrict__ aout) {
  __shared__ ushort Vs[4][64][36];   // V natural layout, rows padded to 72B
  const int wid = threadIdx.x >> 6, lane = threadIdx.x & 63;
  const int linb = (blockIdx.x & 7) * 512 + (blockIdx.x >> 3);  // 4096 = 8*512
  const int u = linb * 4 + wid;
  const int head = u & 7, wl = u >> 3;
  const int b = wl >> 8, wh = (wl >> 4) & 15, ww = wl & 15;
  const int c = lane & 15, g = lane >> 4;
  const int g4 = g * 4, g8 = g * 8;
  const ushort* wb = qkvw + (size_t)wl * 64 * 768;
  const us8 zz = 0;

  const bool e_r0 = (wh == 0), e_r7 = (wh == 15), e_c0 = (ww == 0), e_c7 = (ww == 15);
#define TOKVALID(t) (!(((e_r0) & (((t) >> 3) == 0)) | ((e_r7) & (((t) >> 3) == 7)) | \
                       ((e_c0) & (((t) & 7) == 0)) | ((e_c7) & (((t) & 7) == 7))))

  // stage V (all 32 dims, masked)
  {
    const bool tv = TOKVALID(lane);
    const ushort* vp = wb + (size_t)lane * 768 + 512 + head * 32;
    us8 v0 = *(const us8*)vp;
    us8 v1 = *(const us8*)(vp + 8);
    us8 v2 = *(const us8*)(vp + 16);
    us8 v3 = *(const us8*)(vp + 24);
    v0 = tv ? v0 : zz;
    v1 = tv ? v1 : zz;
    v2 = tv ? v2 : zz;
    v3 = tv ? v3 : zz;
    ushort* vr = &Vs[wid][lane][0];
    *(us4*)&vr[0]  = __builtin_shufflevector(v0, v0, 0, 1, 2, 3);
    *(us4*)&vr[4]  = __builtin_shufflevector(v0, v0, 4, 5, 6, 7);
    *(us4*)&vr[8]  = __builtin_shufflevector(v1, v1, 0, 1, 2, 3);
    *(us4*)&vr[12] = __builtin_shufflevector(v1, v1, 4, 5, 6, 7);
    *(us4*)&vr[16] = __builtin_shufflevector(v2, v2, 0, 1, 2, 3);
    *(us4*)&vr[20] = __builtin_shufflevector(v2, v2, 4, 5, 6, 7);
    *(us4*)&vr[24] = __builtin_shufflevector(v3, v3, 0, 1, 2, 3);
    *(us4*)&vr[28] = __builtin_shufflevector(v3, v3, 4, 5, 6, 7);
  }

  // QK^T (swapped): A = K fragments, B = Q fragments; zero invalid fragments
  bf16x8 kf[4], qf[4];
#pragma unroll
  for (int ki = 0; ki < 4; ++ki) {
    const int tk = ki * 16 + c;
    us8 kv = *(const us8*)&wb[(size_t)tk * 768 + 256 + head * 32 + g8];
    kv = TOKVALID(tk) ? kv : zz;
    kf[ki] = __builtin_bit_cast(bf16x8, kv);
  }
#pragma unroll
  for (int qj = 0; qj < 4; ++qj) {
    const int tq = qj * 16 + c;
    us8 qv = *(const us8*)&wb[(size_t)tq * 768 + head * 32 + g8];
    qv = TOKVALID(tq) ? qv : zz;
    qf[qj] = __builtin_bit_cast(bf16x8, qv);
  }

  // bias fragment = MFMA C-input: biasV[head][ki][g][q][r]
  const float* bvh = biasV + (head << 12);
  f32x4 st[4][4];
#pragma unroll
  for (int ki = 0; ki < 4; ++ki)
#pragma unroll
    for (int qj = 0; qj < 4; ++qj) {
      const f32x4 bfrag = *(const f32x4*)&bvh[((ki * 4 + g) << 8) + ((qj * 16 + c) << 2)];
      st[ki][qj] = __builtin_amdgcn_mfma_f32_16x16x32_bf16(kf[ki], qf[qj], bfrag, 0, 0, 0);
    }

  // softmax + in-register P transpose
  unsigned afr[4][2][4];
#pragma unroll
  for (int qj = 0; qj < 4; ++qj) {
    float s[16];
#pragma unroll
    for (int ki = 0; ki < 4; ++ki)
#pragma unroll
      for (int r = 0; r < 4; ++r) {
        const int key = ki * 16 + g4 + r;
        s[ki * 4 + r] = TOKVALID(key) ? st[ki][qj][r] : -1e30f;
      }
    float m = s[0];
#pragma unroll
    for (int i = 1; i < 16; ++i) m = fmaxf(m, s[i]);
    m = fmaxf(m, __shfl_xor(m, 16));
    m = fmaxf(m, __shfl_xor(m, 32));
    float den = 0.f;
#pragma unroll
    for (int i = 0; i < 16; ++i) { s[i] = __expf(s[i] - m); den += s[i]; }
    den += __shfl_xor(den, 16);
    den += __shfl_xor(den, 32);
    const float inv = 1.f / den;

    unsigned pk[4][2];
#pragma unroll
    for (int ki = 0; ki < 4; ++ki) {
      pk[ki][0] = ((unsigned)f2bf(s[ki * 4 + 1] * inv) << 16) | f2bf(s[ki * 4 + 0] * inv);
      pk[ki][1] = ((unsigned)f2bf(s[ki * 4 + 3] * inv) << 16) | f2bf(s[ki * 4 + 2] * inv);
    }
#pragma unroll
    for (int j2 = 0; j2 < 4; ++j2) {
      const int src = c + 16 * (2 * (g & 1) + (j2 >> 1));
      const unsigned s0 = __shfl(pk[0][j2 & 1], src);
      const unsigned s1 = __shfl(pk[1][j2 & 1], src);
      const unsigned s2 = __shfl(pk[2][j2 & 1], src);
      const unsigned s3 = __shfl(pk[3][j2 & 1], src);
      afr[qj][0][j2] = (g < 2) ? s0 : s1;
      afr[qj][1][j2] = (g < 2) ? s2 : s3;
    }
  }

  // PV
  f32x4 ao[4][2];
#pragma unroll
  for (int qi = 0; qi < 4; ++qi)
#pragma unroll
    for (int di = 0; di < 2; ++di) ao[qi][di] = 0.f;
#pragma unroll
  for (int kc = 0; kc < 2; ++kc) {
#pragma unroll
    for (int di = 0; di < 2; ++di) {
      us8 bv;
#pragma unroll
      for (int j = 0; j < 8; ++j) bv[j] = Vs[wid][kc * 32 + g8 + j][di * 16 + c];
      const bf16x8 bb = __builtin_bit_cast(bf16x8, bv);
#pragma unroll
      for (int qi = 0; qi < 4; ++qi) {
        const u32x4v aw4 = {afr[qi][kc][0], afr[qi][kc][1], afr[qi][kc][2], afr[qi][kc][3]};
        ao[qi][di] = __builtin_amdgcn_mfma_f32_16x16x32_bf16(
            __builtin_bit_cast(bf16x8, aw4), bb, ao[qi][di], 0, 0, 0);
      }
    }
  }

#pragma unroll
  for (int qi = 0; qi < 4; ++qi)
#pragma unroll
    for (int r = 0; r < 4; ++r) {
      const int q = qi * 16 + g4 + r;
      if (TOKVALID(q)) {
        const int h = (q >> 3) * 16 + wh - 1, w2 = (q & 7) * 16 + ww - 1;
        ushort* op = aout + ((size_t)((b * HDIM + h) * WDIM + w2)) * 256 + head * 32;
        op[c] = f2bf(ao[qi][0][r]);
        op[16 + c] = f2bf(ao[qi][1][r]);
      }
    }
#undef TOKVALID
}

// ---------------- launch ----------------
extern "C" void kernel_launch(void* const* d_in, const int* in_sizes, int n_in,
                              void* d_out, int out_size, void* d_ws, size_t ws_size,
                              hipStream_t stream) {
  (void)in_sizes; (void)n_in; (void)out_size; (void)ws_size;
  const float* x      = (const float*)d_in[0];
  const float* w_qkv  = (const float*)d_in[1];
  const float* w_dw   = (const float*)d_in[2];
  const float* ln_g   = (const float*)d_in[3];
  const float* ln_b   = (const float*)d_in[4];
  const float* q_bias = (const float*)d_in[5];
  const float* v_bias = (const float*)d_in[6];
  const float* scale  = (const float*)d_in[7];
  const float* cpb_w0 = (const float*)d_in[8];
  const float* cpb_b0 = (const float*)d_in[9];
  const float* cpb_w1 = (const float*)d_in[10];
  const float* w_proj = (const float*)d_in[11];
  float* out = (float*)d_out;

  char* ws = (char*)d_ws;
  const size_t PRE  = (size_t)NPIX * 768 * 2;     // qkv_pre; reused for attn_out
  const size_t QKVW = (size_t)131072 * 768 * 2;   // window-padded qkv
  const size_t WBASE = PRE + QKVW + (size_t)768 * 256 * 2 + (size_t)256 * 256 * 2;
  ushort* pre    = (ushort*)ws;
  ushort* qkvw   = (ushort*)(ws + PRE);
  ushort* xb     = (ushort*)(ws + PRE);           // bf16 x, parked in qkvw region
  ushort* aoutb  = pre;
  ushort* wqkvT  = (ushort*)(ws + PRE + QKVW);
  ushort* wprojT = (ushort*)(ws + PRE + QKVW + (size_t)768 * 256 * 2);
  float*  cpbtmp = (float*)(ws + WBASE);
  float*  biasV  = (float*)(ws + WBASE + 8192);
  float*  beta2  = (float*)(ws + WBASE + 8192 + 131072);

  k_cvt_wT<<<768, 256, 0, stream>>>(w_qkv, wqkvT, 768, 256);
  k_cvt_wT<<<256, 256, 0, stream>>>(w_proj, wprojT, 256, 256);
  k_cpb1<<<57, 256, 0, stream>>>(cpb_w0, cpb_b0, cpb_w1, cpbtmp);
  k_cpb2<<<128, 256, 0, stream>>>(cpbtmp, biasV);
  k_fuseb<<<3, 256, 0, stream>>>(ln_b, q_bias, v_bias, beta2);
  k_cvt_x<<<2048, 256, 0, stream>>>(x, xb, NPIX * 256 / 8);
  k_gemm<0, 6><<<5958, 256, 0, stream>>>(xb, wqkvT, pre, NPIX, 768);
  k_convln<<<21168, 192, 0, stream>>>(pre, w_dw, ln_g, beta2, scale, qkvw);
  k_attn<<<4096, 256, 0, stream>>>(qkvw, biasV, aoutb);
  k_gemm<1, 2><<<1986, 256, 0, stream>>>(aoutb, wprojT, out, NPIX, 256);
}